// Round 7
// baseline (436.843 us; speedup 1.0000x reference)
//
#include <hip/hip_runtime.h>

// ---- problem constants ----
#define BATCH 2
#define DIN 65
#define D2IN (65*65)
#define D3IN (65*65*65)
#define D3P 274628      // padded per-batch sidx stride (16B-aligned)
#define NTOT (2*D3IN)   // 549250
#define DO 32
#define DP 34           // padded 32 + 2 halo
#define C2 32
#define CO 100
#define CAP 8192        // per parity-class capacity
#define EPS 1e-5f

typedef __attribute__((ext_vector_type(8))) short short8;
typedef __attribute__((ext_vector_type(4))) float floatx4;

// workspace layout (float offsets)
#define H1B_OFF 0                       // bf16 [2][34][34][34][32] -> 1257728 f
#define H2B_OFF 1257728
#define M1_OFF  2515456                 // 65536 f
#define WB2_OFF 2580992                 // 27*2*64*8 bf16 = 13824 f
#define WB3_OFF 2594816                 // 27*7*64*8 bf16 = 48384 f
#define CNT8_OFF (2643200)              // 8 ints (16B-aligned)
#define VOX_OFF 2643208                 // 65536 ints
#define SIDX_OFF 2708744                // 2*274628 = 549256 ints
#define RES_OFF 3258000                 // 16B-aligned; 65536*112 f
// total 10598032 floats ~= 42.4 MB

__device__ __forceinline__ unsigned short f2bf(float f) {
    unsigned int u = __float_as_uint(f);
    return (unsigned short)((u + 0x7fffu + ((u >> 16) & 1u)) >> 16);
}

// ================= F1: fused compact | k1 | shell-zero | weight-pack =================
// blocks [0,512): parity compact; [512,768): conv1; [768,1076): halo shell zero;
// [1076,1137): W2/Winv B-fragment packing. All parts write-disjoint.
__global__ __launch_bounds__(256) void f1(
    const float* __restrict__ x, const int* __restrict__ mask0,
    const float* __restrict__ W1, const float* __restrict__ b1,
    const float* __restrict__ g1, const float* __restrict__ bt1,
    const float* __restrict__ rm1, const float* __restrict__ rv1,
    const float* __restrict__ W2, const float* __restrict__ Winv,
    unsigned short* __restrict__ h1b, unsigned short* __restrict__ h2b,
    float* __restrict__ m1,
    unsigned short* __restrict__ wb2, unsigned short* __restrict__ wb3,
    int* __restrict__ sidxp, int* __restrict__ vox, int* __restrict__ cnt8)
{
    __shared__ int lcnt[8], lbase[8];
    int bid = blockIdx.x, tid = threadIdx.x;

    if (bid < 512) {
        // ---- parity-class compaction (cnt8 pre-zeroed by hipMemsetAsync) ----
        const int chunk = 1073;                 // 512*1073 >= NTOT
        int start = bid * chunk;
        int end = start + chunk; if (end > NTOT) end = NTOT;
        if (tid < 8) lcnt[tid] = 0;
        __syncthreads();
        for (int t = start + tid; t < end; t += 256) {
            if (mask0[t]) {
                int bb = (t >= D3IN) ? 1 : 0;
                int r = t - bb * D3IN;
                int z = r / D2IN; int rem = r % D2IN;
                int y = rem / DIN; int xx = rem % DIN;
                atomicAdd(&lcnt[((z & 1) << 2) | ((y & 1) << 1) | (xx & 1)], 1);
            }
        }
        __syncthreads();
        if (tid < 8) {
            lbase[tid] = lcnt[tid] ? atomicAdd(&cnt8[tid], lcnt[tid]) : 0;
            lcnt[tid] = 0;
        }
        __syncthreads();
        for (int t = start + tid; t < end; t += 256) {
            int bb = (t >= D3IN) ? 1 : 0;
            int r = t - bb * D3IN;
            int s = -1;
            if (mask0[t]) {
                int z = r / D2IN; int rem = r % D2IN;
                int y = rem / DIN; int xx = rem % DIN;
                int cls = ((z & 1) << 2) | ((y & 1) << 1) | (xx & 1);
                int loff = atomicAdd(&lcnt[cls], 1);
                int slot = lbase[cls] + loff;
                if (slot < CAP) {
                    s = cls * CAP + slot;
                    vox[s] = (bb << 21) | (z << 14) | (y << 7) | xx;
                }
            }
            sidxp[bb * D3P + r] = s;
        }
    } else if (bid < 768) {
        // ---- conv1(1->32,s2) + BN + ReLU + mask -> h1 bf16 (interior) ----
        int t = (bid - 512) * 256 + tid;   // 65536 voxels exactly
        int b = t >> 15, r = t & 32767;
        int z = r >> 10, y = (r >> 5) & 31, xo = r & 31;

        const float* xb = x + b * D3IN;
        const int*   mb = mask0 + b * D3IN;

        float xv[27];
        int any = 0;
#pragma unroll
        for (int kd = 0; kd < 3; kd++)
#pragma unroll
            for (int kh = 0; kh < 3; kh++)
#pragma unroll
                for (int kw = 0; kw < 3; kw++) {
                    int idx = (2 * z + kd) * D2IN + (2 * y + kh) * DIN + (2 * xo + kw);
                    xv[kd * 9 + kh * 3 + kw] = xb[idx];
                    any |= mb[idx];
                }
        float m1f = any ? 1.0f : 0.0f;
        m1[t] = m1f;

        union { unsigned short h[32]; uint4 v[4]; } u;
#pragma unroll 4
        for (int co = 0; co < 32; co++) {
            float a = 0.f;
#pragma unroll
            for (int k = 0; k < 27; k++) a += xv[k] * W1[co * 27 + k];
            float s = g1[co] * rsqrtf(rv1[co] + EPS);
            float v = (a + b1[co] - rm1[co]) * s + bt1[co];
            u.h[co] = f2bf(fmaxf(v, 0.f) * m1f);
        }
        uint4* out4 = (uint4*)(h1b + (size_t)((((b * DP + z + 1) * DP + (y + 1)) * DP + (xo + 1)) * C2));
#pragma unroll
        for (int q = 0; q < 4; q++) out4[q] = u.v[q];
    } else if (bid < 1076) {
        // ---- halo shell zero for h1b and h2b ----
        int gid = (bid - 768) * 256 + tid;
        if (gid < 2 * 39304) {
            int b = gid / 39304; int r = gid % 39304;
            int z = r / 1156; int rem = r % 1156;
            int y = rem / 34; int xx = rem % 34;
            if (z == 0 || z == 33 || y == 0 || y == 33 || xx == 0 || xx == 33) {
                size_t off = (size_t)((((b * DP + z) * DP + y) * DP + xx) * C2);
                uint4 zv; zv.x = 0; zv.y = 0; zv.z = 0; zv.w = 0;
                uint4* p1 = (uint4*)(h1b + off);
                uint4* p2 = (uint4*)(h2b + off);
#pragma unroll
                for (int q = 0; q < 4; q++) { p1[q] = zv; p2[q] = zv; }
            }
        }
    } else {
        // ---- pack W2 / Winv into MFMA B-fragment layout ----
        int gid = (bid - 1076) * 256 + tid;
        if (gid < 27 * 2 * 64) {
            int q = gid;
            int tap = q >> 7, r = q & 127, ct = r >> 6, lane = r & 63;
            int n = ct * 16 + (lane & 15), kq = lane >> 4;
            union { unsigned short h[8]; uint4 v; } u;
#pragma unroll
            for (int j = 0; j < 8; j++) {
                int k = kq * 8 + j;
                u.h[j] = f2bf(W2[n * 864 + k * 27 + tap]);
            }
            *(uint4*)(wb2 + q * 8) = u.v;
        } else if (gid < 27 * 2 * 64 + 27 * 7 * 64) {
            int q = gid - 27 * 2 * 64;
            int tap = q / 448, r = q % 448, ct = r >> 6, lane = r & 63;
            int co = ct * 16 + (lane & 15), kq = lane >> 4;
            union { unsigned short h[8]; uint4 v; } u;
#pragma unroll
            for (int j = 0; j < 8; j++) {
                int k = kq * 8 + j;
                u.h[j] = (co < 100) ? f2bf(Winv[(co * 32 + k) * 27 + tap]) : (unsigned short)0;
            }
            *(uint4*)(wb3 + q * 8) = u.v;
        }
    }
}

// ---------------- k2: conv2 as MFMA gather-GEMM; h2 bf16 out ----------------
__global__ __launch_bounds__(256) void k2(
    const unsigned short* __restrict__ h1b, const unsigned short* __restrict__ wb2,
    const float* __restrict__ b2, const float* __restrict__ g2,
    const float* __restrict__ bt2, const float* __restrict__ rm2,
    const float* __restrict__ rv2, const float* __restrict__ m1,
    unsigned short* __restrict__ h2b)
{
    int tid = threadIdx.x;
    int wv = tid >> 6, lane = tid & 63;
    int mtile = blockIdx.x * 4 + wv;      // [0,4096)
    int v0 = mtile * 16;
    int b = v0 >> 15, r = v0 & 32767;
    int z = r >> 10, y = (r >> 5) & 31, x0 = r & 31;

    int m = lane & 15, kq = lane >> 4;
    const unsigned short* abase = h1b +
        (size_t)((((b * DP + z) * DP + y) * DP + x0 + m) * C2 + kq * 8);

    floatx4 acc[2];
    acc[0] = (floatx4){0.f, 0.f, 0.f, 0.f};
    acc[1] = (floatx4){0.f, 0.f, 0.f, 0.f};

    for (int kd = 0; kd < 3; kd++)
#pragma unroll
        for (int kh = 0; kh < 3; kh++)
#pragma unroll
            for (int kw = 0; kw < 3; kw++) {
                int tap = (kd * 3 + kh) * 3 + kw;
                short8 a = *(const short8*)(abase + ((kd * DP + kh) * DP + kw) * C2);
                short8 w0 = *(const short8*)(wb2 + ((tap * 2 + 0) * 64 + lane) * 8);
                short8 w1 = *(const short8*)(wb2 + ((tap * 2 + 1) * 64 + lane) * 8);
                acc[0] = __builtin_amdgcn_mfma_f32_16x16x32_bf16(a, w0, acc[0], 0, 0, 0);
                acc[1] = __builtin_amdgcn_mfma_f32_16x16x32_bf16(a, w1, acc[1], 0, 0, 0);
            }

    float mf[4];
#pragma unroll
    for (int i = 0; i < 4; i++) mf[i] = m1[v0 + kq * 4 + i];
#pragma unroll
    for (int ct = 0; ct < 2; ct++) {
        int co = ct * 16 + m;
        float s = g2[co] * rsqrtf(rv2[co] + EPS);
        float sh = (b2[co] - rm2[co]) * s + bt2[co];
#pragma unroll
        for (int i = 0; i < 4; i++) {
            int row = kq * 4 + i;
            float val = fmaxf(acc[ct][i] * s + sh, 0.f) * mf[i];
            h2b[(size_t)((((b * DP + z + 1) * DP + (y + 1)) * DP + (x0 + row + 1)) * C2 + co)]
                = f2bf(val);
        }
    }
}

// ---------------- k3compute: inverse conv as MFMA gather-GEMM; res stride 112 ----------------
__global__ __launch_bounds__(256) void k3compute(
    const unsigned short* __restrict__ h2b, const unsigned short* __restrict__ wb3,
    const float* __restrict__ binv, const int* __restrict__ vox,
    const int* __restrict__ cnt8, float* __restrict__ res)
{
    int cls = blockIdx.y;
    int pd = (cls >> 2) & 1, ph = (cls >> 1) & 1, pw = cls & 1;
    int nh = 2 - ph, nw = 2 - pw, nhw = nh * nw;
    int ntap = (2 - pd) * nhw;
    int tid = threadIdx.x;
    int wv = tid >> 6, lane = tid & 63;
    int m = lane & 15, kq = lane >> 4;

    int n = cnt8[cls]; if (n > CAP) n = CAP;
    int ntiles = (n + 15) >> 4;

    float bv[7];
#pragma unroll
    for (int ct = 0; ct < 7; ct++) {
        int co = ct * 16 + m;
        bv[ct] = (co < 100) ? binv[co] : 0.f;
    }

    for (int t = blockIdx.x * 4 + wv; t < ntiles; t += 64 * 4) {
        int idx = t * 16 + m; if (idx >= n) idx = n - 1;
        unsigned int pv = (unsigned int)vox[cls * CAP + idx];
        int xx = pv & 127, yy = (pv >> 7) & 127, zz = (pv >> 14) & 127, bb = (pv >> 21) & 1;
        const unsigned short* abase = h2b +
            (size_t)(((((bb * DP + (zz >> 1) + pd) * DP + (yy >> 1) + ph) * DP
                       + (xx >> 1) + pw)) * C2 + kq * 8);

        floatx4 acc[7];
#pragma unroll
        for (int ct = 0; ct < 7; ct++) acc[ct] = (floatx4){0.f, 0.f, 0.f, 0.f};

        for (int tl = 0; tl < ntap; tl++) {
            int td = tl / nhw, rr = tl % nhw, th = rr / nw, tw = rr % nw;
            int tap = (pd + 2 * td) * 9 + (ph + 2 * th) * 3 + (pw + 2 * tw);
            short8 a = *(const short8*)(abase + ((td * DP + th) * DP + tw) * C2);
#pragma unroll
            for (int ct = 0; ct < 7; ct++) {
                short8 w = *(const short8*)(wb3 + ((tap * 7 + ct) * 64 + lane) * 8);
                acc[ct] = __builtin_amdgcn_mfma_f32_16x16x32_bf16(a, w, acc[ct], 0, 0, 0);
            }
        }
#pragma unroll
        for (int ct = 0; ct < 7; ct++) {
            int co = ct * 16 + m;
#pragma unroll
            for (int i = 0; i < 4; i++) {
                int ridx = t * 16 + kq * 4 + i;
                if (ridx < n)
                    res[(size_t)(cls * CAP + ridx) * 112 + co] = acc[ct][i] + bv[ct];
            }
        }
    }
}

// ---------------- k3write v4: flat-aligned float4 dense writer ----------------
// grid (269, 200): blockIdx.y = plane p = b*100+co. One float4 group per thread,
// 16B-aligned in the flat out buffer; plane-edge floats handled by block 0.
__global__ __launch_bounds__(256) void k3write(
    const float* __restrict__ res, const int* __restrict__ sidxp,
    float* __restrict__ out)
{
    int p = blockIdx.y;
    int b = p / 100, co = p % 100;
    size_t plane_off = (size_t)p * D3IN;
    size_t gs = (plane_off + 3) >> 2;          // first full group
    size_t ge = (plane_off + D3IN) >> 2;       // end of full groups
    const int* sb = sidxp + b * D3P;

    size_t g = gs + (size_t)blockIdx.x * 256 + threadIdx.x;
    if (g < ge) {
        int r0 = (int)(4 * g - plane_off);
        int s0 = sb[r0], s1 = sb[r0 + 1], s2 = sb[r0 + 2], s3 = sb[r0 + 3];
        float4 v;
        v.x = (s0 >= 0) ? res[(size_t)s0 * 112 + co] : 0.f;
        v.y = (s1 >= 0) ? res[(size_t)s1 * 112 + co] : 0.f;
        v.z = (s2 >= 0) ? res[(size_t)s2 * 112 + co] : 0.f;
        v.w = (s3 >= 0) ? res[(size_t)s3 * 112 + co] : 0.f;
        *(float4*)(out + 4 * g) = v;
    }
    if (blockIdx.x == 0) {
        int tid = threadIdx.x;
        int nhd = (int)(4 * gs - plane_off);                 // 0..3 head floats
        int ntl = (int)(plane_off + D3IN - 4 * ge);          // 0..3 tail floats
        if (tid < nhd) {
            int s = sb[tid];
            out[plane_off + tid] = (s >= 0) ? res[(size_t)s * 112 + co] : 0.f;
        } else if (tid >= 8 && tid < 8 + ntl) {
            int r = (int)(4 * ge - plane_off) + (tid - 8);
            int s = sb[r];
            out[4 * ge + (tid - 8)] = (s >= 0) ? res[(size_t)s * 112 + co] : 0.f;
        }
    }
}

extern "C" void kernel_launch(void* const* d_in, const int* in_sizes, int n_in,
                              void* d_out, int out_size, void* d_ws, size_t ws_size,
                              hipStream_t stream) {
    const float* x    = (const float*)d_in[0];
    const int*  mask0 = (const int*)  d_in[1];
    const float* W1   = (const float*)d_in[2];
    const float* b1   = (const float*)d_in[3];
    const float* g1   = (const float*)d_in[4];
    const float* bt1  = (const float*)d_in[5];
    const float* rm1  = (const float*)d_in[6];
    const float* rv1  = (const float*)d_in[7];
    const float* W2   = (const float*)d_in[8];
    const float* b2   = (const float*)d_in[9];
    const float* g2   = (const float*)d_in[10];
    const float* bt2  = (const float*)d_in[11];
    const float* rm2  = (const float*)d_in[12];
    const float* rv2  = (const float*)d_in[13];
    const float* Winv = (const float*)d_in[14];
    const float* binv = (const float*)d_in[15];

    float* ws = (float*)d_ws;
    unsigned short* h1b = (unsigned short*)(ws + H1B_OFF);
    unsigned short* h2b = (unsigned short*)(ws + H2B_OFF);
    float* m1   = ws + M1_OFF;
    unsigned short* wb2 = (unsigned short*)(ws + WB2_OFF);
    unsigned short* wb3 = (unsigned short*)(ws + WB3_OFF);
    int*   cnt8 = (int*)(ws + CNT8_OFF);
    int*   vox  = (int*)(ws + VOX_OFF);
    int*   sidxp= (int*)(ws + SIDX_OFF);
    float* res  = ws + RES_OFF;

    hipMemsetAsync(cnt8, 0, 8 * sizeof(int), stream);

    f1<<<1137, 256, 0, stream>>>(x, mask0, W1, b1, g1, bt1, rm1, rv1, W2, Winv,
                                 h1b, h2b, m1, wb2, wb3, sidxp, vox, cnt8);

    k2<<<1024, 256, 0, stream>>>(h1b, wb2, b2, g2, bt2, rm2, rv2, m1, h2b);

    k3compute<<<dim3(64, 8), 256, 0, stream>>>(h2b, wb3, binv, vox, cnt8, res);

    k3write<<<dim3(269, 200), 256, 0, stream>>>(res, sidxp, (float*)d_out);
}

// Round 8
// 369.477 us; speedup vs baseline: 1.1823x; 1.1823x over previous
//
#include <hip/hip_runtime.h>

// ---- problem constants ----
#define BATCH 2
#define DIN 65
#define D2IN (65*65)
#define D3IN (65*65*65)
#define D3P 274628      // padded per-batch sidx stride (16B-aligned)
#define NTOT (2*D3IN)   // 549250
#define DO 32
#define DP 34           // padded 32 + 2 halo
#define C2 32
#define CO 100
#define CAP 8192        // per parity-class capacity
#define EPS 1e-5f

typedef __attribute__((ext_vector_type(8))) short short8;
typedef __attribute__((ext_vector_type(4))) float floatx4;

// workspace layout (float offsets)
#define H1B_OFF 0                       // bf16 [2][34][34][34][32] -> 1257728 f
#define H2B_OFF 1257728
#define M1_OFF  2515456                 // 65536 f
#define WB2_OFF 2580992                 // 27*2*64*8 bf16 = 13824 f
#define WB3_OFF 2594816                 // 27*7*64*8 bf16 = 48384 f
#define CNT8_OFF (2643200)              // 8 ints (16B-aligned)
#define VOX_OFF 2643208                 // 65536 ints
#define SIDX_OFF 2708744                // 2*274628 = 549256 ints
#define RES_OFF 3258000                 // 16B-aligned; 65536*112 f
// total 10598032 floats ~= 42.4 MB

__device__ __forceinline__ unsigned short f2bf(float f) {
    unsigned int u = __float_as_uint(f);
    return (unsigned short)((u + 0x7fffu + ((u >> 16) & 1u)) >> 16);
}

// ================= F1: fused compact | k1 | shell-zero | weight-pack =================
// blocks [0,512): parity compact; [512,768): conv1; [768,1076): halo shell zero;
// [1076,1137): W2/Winv B-fragment packing. All parts write-disjoint.
__global__ __launch_bounds__(256) void f1(
    const float* __restrict__ x, const int* __restrict__ mask0,
    const float* __restrict__ W1, const float* __restrict__ b1,
    const float* __restrict__ g1, const float* __restrict__ bt1,
    const float* __restrict__ rm1, const float* __restrict__ rv1,
    const float* __restrict__ W2, const float* __restrict__ Winv,
    unsigned short* __restrict__ h1b, unsigned short* __restrict__ h2b,
    float* __restrict__ m1,
    unsigned short* __restrict__ wb2, unsigned short* __restrict__ wb3,
    int* __restrict__ sidxp, int* __restrict__ vox, int* __restrict__ cnt8)
{
    __shared__ int lcnt[8], lbase[8];
    int bid = blockIdx.x, tid = threadIdx.x;

    if (bid < 512) {
        // ---- parity-class compaction (cnt8 pre-zeroed by hipMemsetAsync) ----
        const int chunk = 1073;                 // 512*1073 >= NTOT
        int start = bid * chunk;
        int end = start + chunk; if (end > NTOT) end = NTOT;
        if (tid < 8) lcnt[tid] = 0;
        __syncthreads();
        for (int t = start + tid; t < end; t += 256) {
            if (mask0[t]) {
                int bb = (t >= D3IN) ? 1 : 0;
                int r = t - bb * D3IN;
                int z = r / D2IN; int rem = r % D2IN;
                int y = rem / DIN; int xx = rem % DIN;
                atomicAdd(&lcnt[((z & 1) << 2) | ((y & 1) << 1) | (xx & 1)], 1);
            }
        }
        __syncthreads();
        if (tid < 8) {
            lbase[tid] = lcnt[tid] ? atomicAdd(&cnt8[tid], lcnt[tid]) : 0;
            lcnt[tid] = 0;
        }
        __syncthreads();
        for (int t = start + tid; t < end; t += 256) {
            int bb = (t >= D3IN) ? 1 : 0;
            int r = t - bb * D3IN;
            int s = -1;
            if (mask0[t]) {
                int z = r / D2IN; int rem = r % D2IN;
                int y = rem / DIN; int xx = rem % DIN;
                int cls = ((z & 1) << 2) | ((y & 1) << 1) | (xx & 1);
                int loff = atomicAdd(&lcnt[cls], 1);
                int slot = lbase[cls] + loff;
                if (slot < CAP) {
                    s = cls * CAP + slot;
                    vox[s] = (bb << 21) | (z << 14) | (y << 7) | xx;
                }
            }
            sidxp[bb * D3P + r] = s;
        }
    } else if (bid < 768) {
        // ---- conv1(1->32,s2) + BN + ReLU + mask -> h1 bf16 (interior) ----
        int t = (bid - 512) * 256 + tid;   // 65536 voxels exactly
        int b = t >> 15, r = t & 32767;
        int z = r >> 10, y = (r >> 5) & 31, xo = r & 31;

        const float* xb = x + b * D3IN;
        const int*   mb = mask0 + b * D3IN;

        float xv[27];
        int any = 0;
#pragma unroll
        for (int kd = 0; kd < 3; kd++)
#pragma unroll
            for (int kh = 0; kh < 3; kh++)
#pragma unroll
                for (int kw = 0; kw < 3; kw++) {
                    int idx = (2 * z + kd) * D2IN + (2 * y + kh) * DIN + (2 * xo + kw);
                    xv[kd * 9 + kh * 3 + kw] = xb[idx];
                    any |= mb[idx];
                }
        float m1f = any ? 1.0f : 0.0f;
        m1[t] = m1f;

        union { unsigned short h[32]; uint4 v[4]; } u;
#pragma unroll 4
        for (int co = 0; co < 32; co++) {
            float a = 0.f;
#pragma unroll
            for (int k = 0; k < 27; k++) a += xv[k] * W1[co * 27 + k];
            float s = g1[co] * rsqrtf(rv1[co] + EPS);
            float v = (a + b1[co] - rm1[co]) * s + bt1[co];
            u.h[co] = f2bf(fmaxf(v, 0.f) * m1f);
        }
        uint4* out4 = (uint4*)(h1b + (size_t)((((b * DP + z + 1) * DP + (y + 1)) * DP + (xo + 1)) * C2));
#pragma unroll
        for (int q = 0; q < 4; q++) out4[q] = u.v[q];
    } else if (bid < 1076) {
        // ---- halo shell zero for h1b and h2b ----
        int gid = (bid - 768) * 256 + tid;
        if (gid < 2 * 39304) {
            int b = gid / 39304; int r = gid % 39304;
            int z = r / 1156; int rem = r % 1156;
            int y = rem / 34; int xx = rem % 34;
            if (z == 0 || z == 33 || y == 0 || y == 33 || xx == 0 || xx == 33) {
                size_t off = (size_t)((((b * DP + z) * DP + y) * DP + xx) * C2);
                uint4 zv; zv.x = 0; zv.y = 0; zv.z = 0; zv.w = 0;
                uint4* p1 = (uint4*)(h1b + off);
                uint4* p2 = (uint4*)(h2b + off);
#pragma unroll
                for (int q = 0; q < 4; q++) { p1[q] = zv; p2[q] = zv; }
            }
        }
    } else {
        // ---- pack W2 / Winv into MFMA B-fragment layout ----
        int gid = (bid - 1076) * 256 + tid;
        if (gid < 27 * 2 * 64) {
            int q = gid;
            int tap = q >> 7, r = q & 127, ct = r >> 6, lane = r & 63;
            int n = ct * 16 + (lane & 15), kq = lane >> 4;
            union { unsigned short h[8]; uint4 v; } u;
#pragma unroll
            for (int j = 0; j < 8; j++) {
                int k = kq * 8 + j;
                u.h[j] = f2bf(W2[n * 864 + k * 27 + tap]);
            }
            *(uint4*)(wb2 + q * 8) = u.v;
        } else if (gid < 27 * 2 * 64 + 27 * 7 * 64) {
            int q = gid - 27 * 2 * 64;
            int tap = q / 448, r = q % 448, ct = r >> 6, lane = r & 63;
            int co = ct * 16 + (lane & 15), kq = lane >> 4;
            union { unsigned short h[8]; uint4 v; } u;
#pragma unroll
            for (int j = 0; j < 8; j++) {
                int k = kq * 8 + j;
                u.h[j] = (co < 100) ? f2bf(Winv[(co * 32 + k) * 27 + tap]) : (unsigned short)0;
            }
            *(uint4*)(wb3 + q * 8) = u.v;
        }
    }
}

// ---------------- k2: conv2 as MFMA gather-GEMM; h2 bf16 out ----------------
__global__ __launch_bounds__(256) void k2(
    const unsigned short* __restrict__ h1b, const unsigned short* __restrict__ wb2,
    const float* __restrict__ b2, const float* __restrict__ g2,
    const float* __restrict__ bt2, const float* __restrict__ rm2,
    const float* __restrict__ rv2, const float* __restrict__ m1,
    unsigned short* __restrict__ h2b)
{
    int tid = threadIdx.x;
    int wv = tid >> 6, lane = tid & 63;
    int mtile = blockIdx.x * 4 + wv;      // [0,4096)
    int v0 = mtile * 16;
    int b = v0 >> 15, r = v0 & 32767;
    int z = r >> 10, y = (r >> 5) & 31, x0 = r & 31;

    int m = lane & 15, kq = lane >> 4;
    const unsigned short* abase = h1b +
        (size_t)((((b * DP + z) * DP + y) * DP + x0 + m) * C2 + kq * 8);

    floatx4 acc[2];
    acc[0] = (floatx4){0.f, 0.f, 0.f, 0.f};
    acc[1] = (floatx4){0.f, 0.f, 0.f, 0.f};

    for (int kd = 0; kd < 3; kd++)
#pragma unroll
        for (int kh = 0; kh < 3; kh++)
#pragma unroll
            for (int kw = 0; kw < 3; kw++) {
                int tap = (kd * 3 + kh) * 3 + kw;
                short8 a = *(const short8*)(abase + ((kd * DP + kh) * DP + kw) * C2);
                short8 w0 = *(const short8*)(wb2 + ((tap * 2 + 0) * 64 + lane) * 8);
                short8 w1 = *(const short8*)(wb2 + ((tap * 2 + 1) * 64 + lane) * 8);
                acc[0] = __builtin_amdgcn_mfma_f32_16x16x32_bf16(a, w0, acc[0], 0, 0, 0);
                acc[1] = __builtin_amdgcn_mfma_f32_16x16x32_bf16(a, w1, acc[1], 0, 0, 0);
            }

    float mf[4];
#pragma unroll
    for (int i = 0; i < 4; i++) mf[i] = m1[v0 + kq * 4 + i];
#pragma unroll
    for (int ct = 0; ct < 2; ct++) {
        int co = ct * 16 + m;
        float s = g2[co] * rsqrtf(rv2[co] + EPS);
        float sh = (b2[co] - rm2[co]) * s + bt2[co];
#pragma unroll
        for (int i = 0; i < 4; i++) {
            int row = kq * 4 + i;
            float val = fmaxf(acc[ct][i] * s + sh, 0.f) * mf[i];
            h2b[(size_t)((((b * DP + z + 1) * DP + (y + 1)) * DP + (x0 + row + 1)) * C2 + co)]
                = f2bf(val);
        }
    }
}

// ---------------- k3compute: inverse conv as MFMA gather-GEMM; res stride 112 ----------------
__global__ __launch_bounds__(256) void k3compute(
    const unsigned short* __restrict__ h2b, const unsigned short* __restrict__ wb3,
    const float* __restrict__ binv, const int* __restrict__ vox,
    const int* __restrict__ cnt8, float* __restrict__ res)
{
    int cls = blockIdx.y;
    int pd = (cls >> 2) & 1, ph = (cls >> 1) & 1, pw = cls & 1;
    int nh = 2 - ph, nw = 2 - pw, nhw = nh * nw;
    int ntap = (2 - pd) * nhw;
    int tid = threadIdx.x;
    int wv = tid >> 6, lane = tid & 63;
    int m = lane & 15, kq = lane >> 4;

    int n = cnt8[cls]; if (n > CAP) n = CAP;
    int ntiles = (n + 15) >> 4;

    float bv[7];
#pragma unroll
    for (int ct = 0; ct < 7; ct++) {
        int co = ct * 16 + m;
        bv[ct] = (co < 100) ? binv[co] : 0.f;
    }

    for (int t = blockIdx.x * 4 + wv; t < ntiles; t += 64 * 4) {
        int idx = t * 16 + m; if (idx >= n) idx = n - 1;
        unsigned int pv = (unsigned int)vox[cls * CAP + idx];
        int xx = pv & 127, yy = (pv >> 7) & 127, zz = (pv >> 14) & 127, bb = (pv >> 21) & 1;
        const unsigned short* abase = h2b +
            (size_t)(((((bb * DP + (zz >> 1) + pd) * DP + (yy >> 1) + ph) * DP
                       + (xx >> 1) + pw)) * C2 + kq * 8);

        floatx4 acc[7];
#pragma unroll
        for (int ct = 0; ct < 7; ct++) acc[ct] = (floatx4){0.f, 0.f, 0.f, 0.f};

        for (int tl = 0; tl < ntap; tl++) {
            int td = tl / nhw, rr = tl % nhw, th = rr / nw, tw = rr % nw;
            int tap = (pd + 2 * td) * 9 + (ph + 2 * th) * 3 + (pw + 2 * tw);
            short8 a = *(const short8*)(abase + ((td * DP + th) * DP + tw) * C2);
#pragma unroll
            for (int ct = 0; ct < 7; ct++) {
                short8 w = *(const short8*)(wb3 + ((tap * 7 + ct) * 64 + lane) * 8);
                acc[ct] = __builtin_amdgcn_mfma_f32_16x16x32_bf16(a, w, acc[ct], 0, 0, 0);
            }
        }
#pragma unroll
        for (int ct = 0; ct < 7; ct++) {
            int co = ct * 16 + m;
#pragma unroll
            for (int i = 0; i < 4; i++) {
                int ridx = t * 16 + kq * 4 + i;
                if (ridx < n)
                    res[(size_t)(cls * CAP + ridx) * 112 + co] = acc[ct][i] + bv[ct];
            }
        }
    }
}

// ---------------- k3write v5: LDS-tiled transpose writer ----------------
// grid (4292, 2): block = 64 consecutive flat positions x all 100 co.
// Gather: 4 threads/voxel read the full 448B res row (line-aligned, once).
// Store: wave = 25 co-planes, lane = position -> 256B coalesced dword stores.
__global__ __launch_bounds__(256) void k3write(
    const float* __restrict__ res, const int* __restrict__ sidxp,
    float* __restrict__ out)
{
    __shared__ float tile[64 * 112];   // 28.7 KB
    int blk = blockIdx.x;              // 0..4291
    int b = blockIdx.y;
    int r0 = blk * 64;
    int nv = D3IN - r0; if (nv > 64) nv = 64;
    int tid = threadIdx.x;

    int v = tid >> 2, q = tid & 3;
    if (v < nv) {
        int s = sidxp[b * D3P + r0 + v];
        float4* dst = (float4*)&tile[v * 112 + q * 28];
        if (s >= 0) {
            const float4* src = (const float4*)(res + (size_t)s * 112 + q * 28);
#pragma unroll
            for (int j = 0; j < 7; j++) dst[j] = src[j];
        } else {
            float4 z = make_float4(0.f, 0.f, 0.f, 0.f);
#pragma unroll
            for (int j = 0; j < 7; j++) dst[j] = z;
        }
    }
    __syncthreads();

    int wv = tid >> 6, lane = tid & 63;
    if (lane < nv) {
        float* obase = out + (size_t)b * 100 * D3IN + r0 + lane;
#pragma unroll
        for (int j = 0; j < 25; j++) {
            int co = wv * 25 + j;
            obase[(size_t)co * D3IN] = tile[lane * 112 + co];
        }
    }
}

extern "C" void kernel_launch(void* const* d_in, const int* in_sizes, int n_in,
                              void* d_out, int out_size, void* d_ws, size_t ws_size,
                              hipStream_t stream) {
    const float* x    = (const float*)d_in[0];
    const int*  mask0 = (const int*)  d_in[1];
    const float* W1   = (const float*)d_in[2];
    const float* b1   = (const float*)d_in[3];
    const float* g1   = (const float*)d_in[4];
    const float* bt1  = (const float*)d_in[5];
    const float* rm1  = (const float*)d_in[6];
    const float* rv1  = (const float*)d_in[7];
    const float* W2   = (const float*)d_in[8];
    const float* b2   = (const float*)d_in[9];
    const float* g2   = (const float*)d_in[10];
    const float* bt2  = (const float*)d_in[11];
    const float* rm2  = (const float*)d_in[12];
    const float* rv2  = (const float*)d_in[13];
    const float* Winv = (const float*)d_in[14];
    const float* binv = (const float*)d_in[15];

    float* ws = (float*)d_ws;
    unsigned short* h1b = (unsigned short*)(ws + H1B_OFF);
    unsigned short* h2b = (unsigned short*)(ws + H2B_OFF);
    float* m1   = ws + M1_OFF;
    unsigned short* wb2 = (unsigned short*)(ws + WB2_OFF);
    unsigned short* wb3 = (unsigned short*)(ws + WB3_OFF);
    int*   cnt8 = (int*)(ws + CNT8_OFF);
    int*   vox  = (int*)(ws + VOX_OFF);
    int*   sidxp= (int*)(ws + SIDX_OFF);
    float* res  = ws + RES_OFF;

    hipMemsetAsync(cnt8, 0, 8 * sizeof(int), stream);

    f1<<<1137, 256, 0, stream>>>(x, mask0, W1, b1, g1, bt1, rm1, rv1, W2, Winv,
                                 h1b, h2b, m1, wb2, wb3, sidxp, vox, cnt8);

    k2<<<1024, 256, 0, stream>>>(h1b, wb2, b2, g2, bt2, rm2, rv2, m1, h2b);

    k3compute<<<dim3(64, 8), 256, 0, stream>>>(h2b, wb3, binv, vox, cnt8, res);

    k3write<<<dim3(4292, 2), 256, 0, stream>>>(res, sidxp, (float*)d_out);
}

// Round 9
// 349.272 us; speedup vs baseline: 1.2507x; 1.0578x over previous
//
#include <hip/hip_runtime.h>

// ---- problem constants ----
#define BATCH 2
#define DIN 65
#define D2IN (65*65)
#define D3IN (65*65*65)
#define D3P 274628      // padded per-batch sidx stride (16B-aligned)
#define NTOT (2*D3IN)   // 549250
#define DO 32
#define DP 34           // padded 32 + 2 halo
#define C2 32
#define CO 100
#define CAP 8192        // per parity-class capacity
#define EPS 1e-5f
#define TW 113          // k3write LDS tile row stride (odd -> conflict-free column reads)

typedef __attribute__((ext_vector_type(8))) short short8;
typedef __attribute__((ext_vector_type(4))) float floatx4;

// workspace layout (float offsets)
#define H1B_OFF 0                       // bf16 [2][34][34][34][32] -> 1257728 f
#define H2B_OFF 1257728
#define M1_OFF  2515456                 // 65536 f
#define WB2_OFF 2580992                 // 27*2*64*8 bf16 = 13824 f
#define WB3_OFF 2594816                 // 27*7*64*8 bf16 = 48384 f
#define CNT8_OFF (2643200)              // 8 ints (16B-aligned)
#define VOX_OFF 2643208                 // 65536 ints
#define SIDX_OFF 2708744                // 2*274628 = 549256 ints
#define RES_OFF 3258000                 // 16B-aligned; 65536*112 f
// total 10598032 floats ~= 42.4 MB

__device__ __forceinline__ unsigned short f2bf(float f) {
    unsigned int u = __float_as_uint(f);
    return (unsigned short)((u + 0x7fffu + ((u >> 16) & 1u)) >> 16);
}

// ================= F1: fused compact | k1 | shell-zero | weight-pack =================
// blocks [0,512): parity compact; [512,768): conv1; [768,1076): halo shell zero;
// [1076,1137): W2/Winv B-fragment packing. All parts write-disjoint.
__global__ __launch_bounds__(256) void f1(
    const float* __restrict__ x, const int* __restrict__ mask0,
    const float* __restrict__ W1, const float* __restrict__ b1,
    const float* __restrict__ g1, const float* __restrict__ bt1,
    const float* __restrict__ rm1, const float* __restrict__ rv1,
    const float* __restrict__ W2, const float* __restrict__ Winv,
    unsigned short* __restrict__ h1b, unsigned short* __restrict__ h2b,
    float* __restrict__ m1,
    unsigned short* __restrict__ wb2, unsigned short* __restrict__ wb3,
    int* __restrict__ sidxp, int* __restrict__ vox, int* __restrict__ cnt8)
{
    __shared__ int lcnt[8], lbase[8];
    int bid = blockIdx.x, tid = threadIdx.x;

    if (bid < 512) {
        // ---- parity-class compaction (cnt8 pre-zeroed by hipMemsetAsync) ----
        const int chunk = 1073;                 // 512*1073 >= NTOT
        int start = bid * chunk;
        int end = start + chunk; if (end > NTOT) end = NTOT;
        if (tid < 8) lcnt[tid] = 0;
        __syncthreads();
        for (int t = start + tid; t < end; t += 256) {
            if (mask0[t]) {
                int bb = (t >= D3IN) ? 1 : 0;
                int r = t - bb * D3IN;
                int z = r / D2IN; int rem = r % D2IN;
                int y = rem / DIN; int xx = rem % DIN;
                atomicAdd(&lcnt[((z & 1) << 2) | ((y & 1) << 1) | (xx & 1)], 1);
            }
        }
        __syncthreads();
        if (tid < 8) {
            lbase[tid] = lcnt[tid] ? atomicAdd(&cnt8[tid], lcnt[tid]) : 0;
            lcnt[tid] = 0;
        }
        __syncthreads();
        for (int t = start + tid; t < end; t += 256) {
            int bb = (t >= D3IN) ? 1 : 0;
            int r = t - bb * D3IN;
            int s = -1;
            if (mask0[t]) {
                int z = r / D2IN; int rem = r % D2IN;
                int y = rem / DIN; int xx = rem % DIN;
                int cls = ((z & 1) << 2) | ((y & 1) << 1) | (xx & 1);
                int loff = atomicAdd(&lcnt[cls], 1);
                int slot = lbase[cls] + loff;
                if (slot < CAP) {
                    s = cls * CAP + slot;
                    vox[s] = (bb << 21) | (z << 14) | (y << 7) | xx;
                }
            }
            sidxp[bb * D3P + r] = s;
        }
    } else if (bid < 768) {
        // ---- conv1(1->32,s2) + BN + ReLU + mask -> h1 bf16 (interior) ----
        int t = (bid - 512) * 256 + tid;   // 65536 voxels exactly
        int b = t >> 15, r = t & 32767;
        int z = r >> 10, y = (r >> 5) & 31, xo = r & 31;

        const float* xb = x + b * D3IN;
        const int*   mb = mask0 + b * D3IN;

        float xv[27];
        int any = 0;
#pragma unroll
        for (int kd = 0; kd < 3; kd++)
#pragma unroll
            for (int kh = 0; kh < 3; kh++)
#pragma unroll
                for (int kw = 0; kw < 3; kw++) {
                    int idx = (2 * z + kd) * D2IN + (2 * y + kh) * DIN + (2 * xo + kw);
                    xv[kd * 9 + kh * 3 + kw] = xb[idx];
                    any |= mb[idx];
                }
        float m1f = any ? 1.0f : 0.0f;
        m1[t] = m1f;

        union { unsigned short h[32]; uint4 v[4]; } u;
#pragma unroll 4
        for (int co = 0; co < 32; co++) {
            float a = 0.f;
#pragma unroll
            for (int k = 0; k < 27; k++) a += xv[k] * W1[co * 27 + k];
            float s = g1[co] * rsqrtf(rv1[co] + EPS);
            float v = (a + b1[co] - rm1[co]) * s + bt1[co];
            u.h[co] = f2bf(fmaxf(v, 0.f) * m1f);
        }
        uint4* out4 = (uint4*)(h1b + (size_t)((((b * DP + z + 1) * DP + (y + 1)) * DP + (xo + 1)) * C2));
#pragma unroll
        for (int q = 0; q < 4; q++) out4[q] = u.v[q];
    } else if (bid < 1076) {
        // ---- halo shell zero for h1b and h2b ----
        int gid = (bid - 768) * 256 + tid;
        if (gid < 2 * 39304) {
            int b = gid / 39304; int r = gid % 39304;
            int z = r / 1156; int rem = r % 1156;
            int y = rem / 34; int xx = rem % 34;
            if (z == 0 || z == 33 || y == 0 || y == 33 || xx == 0 || xx == 33) {
                size_t off = (size_t)((((b * DP + z) * DP + y) * DP + xx) * C2);
                uint4 zv; zv.x = 0; zv.y = 0; zv.z = 0; zv.w = 0;
                uint4* p1 = (uint4*)(h1b + off);
                uint4* p2 = (uint4*)(h2b + off);
#pragma unroll
                for (int q = 0; q < 4; q++) { p1[q] = zv; p2[q] = zv; }
            }
        }
    } else {
        // ---- pack W2 / Winv into MFMA B-fragment layout ----
        int gid = (bid - 1076) * 256 + tid;
        if (gid < 27 * 2 * 64) {
            int q = gid;
            int tap = q >> 7, r = q & 127, ct = r >> 6, lane = r & 63;
            int n = ct * 16 + (lane & 15), kq = lane >> 4;
            union { unsigned short h[8]; uint4 v; } u;
#pragma unroll
            for (int j = 0; j < 8; j++) {
                int k = kq * 8 + j;
                u.h[j] = f2bf(W2[n * 864 + k * 27 + tap]);
            }
            *(uint4*)(wb2 + q * 8) = u.v;
        } else if (gid < 27 * 2 * 64 + 27 * 7 * 64) {
            int q = gid - 27 * 2 * 64;
            int tap = q / 448, r = q % 448, ct = r >> 6, lane = r & 63;
            int co = ct * 16 + (lane & 15), kq = lane >> 4;
            union { unsigned short h[8]; uint4 v; } u;
#pragma unroll
            for (int j = 0; j < 8; j++) {
                int k = kq * 8 + j;
                u.h[j] = (co < 100) ? f2bf(Winv[(co * 32 + k) * 27 + tap]) : (unsigned short)0;
            }
            *(uint4*)(wb3 + q * 8) = u.v;
        }
    }
}

// ---------------- k2: conv2 as MFMA gather-GEMM; h2 bf16 out ----------------
__global__ __launch_bounds__(256) void k2(
    const unsigned short* __restrict__ h1b, const unsigned short* __restrict__ wb2,
    const float* __restrict__ b2, const float* __restrict__ g2,
    const float* __restrict__ bt2, const float* __restrict__ rm2,
    const float* __restrict__ rv2, const float* __restrict__ m1,
    unsigned short* __restrict__ h2b)
{
    int tid = threadIdx.x;
    int wv = tid >> 6, lane = tid & 63;
    int mtile = blockIdx.x * 4 + wv;      // [0,4096)
    int v0 = mtile * 16;
    int b = v0 >> 15, r = v0 & 32767;
    int z = r >> 10, y = (r >> 5) & 31, x0 = r & 31;

    int m = lane & 15, kq = lane >> 4;
    const unsigned short* abase = h1b +
        (size_t)((((b * DP + z) * DP + y) * DP + x0 + m) * C2 + kq * 8);

    floatx4 acc[2];
    acc[0] = (floatx4){0.f, 0.f, 0.f, 0.f};
    acc[1] = (floatx4){0.f, 0.f, 0.f, 0.f};

    for (int kd = 0; kd < 3; kd++)
#pragma unroll
        for (int kh = 0; kh < 3; kh++)
#pragma unroll
            for (int kw = 0; kw < 3; kw++) {
                int tap = (kd * 3 + kh) * 3 + kw;
                short8 a = *(const short8*)(abase + ((kd * DP + kh) * DP + kw) * C2);
                short8 w0 = *(const short8*)(wb2 + ((tap * 2 + 0) * 64 + lane) * 8);
                short8 w1 = *(const short8*)(wb2 + ((tap * 2 + 1) * 64 + lane) * 8);
                acc[0] = __builtin_amdgcn_mfma_f32_16x16x32_bf16(a, w0, acc[0], 0, 0, 0);
                acc[1] = __builtin_amdgcn_mfma_f32_16x16x32_bf16(a, w1, acc[1], 0, 0, 0);
            }

    float mf[4];
#pragma unroll
    for (int i = 0; i < 4; i++) mf[i] = m1[v0 + kq * 4 + i];
#pragma unroll
    for (int ct = 0; ct < 2; ct++) {
        int co = ct * 16 + m;
        float s = g2[co] * rsqrtf(rv2[co] + EPS);
        float sh = (b2[co] - rm2[co]) * s + bt2[co];
#pragma unroll
        for (int i = 0; i < 4; i++) {
            int row = kq * 4 + i;
            float val = fmaxf(acc[ct][i] * s + sh, 0.f) * mf[i];
            h2b[(size_t)((((b * DP + z + 1) * DP + (y + 1)) * DP + (x0 + row + 1)) * C2 + co)]
                = f2bf(val);
        }
    }
}

// ---------------- k3compute: inverse conv as MFMA gather-GEMM; res stride 112 ----------------
__global__ __launch_bounds__(256) void k3compute(
    const unsigned short* __restrict__ h2b, const unsigned short* __restrict__ wb3,
    const float* __restrict__ binv, const int* __restrict__ vox,
    const int* __restrict__ cnt8, float* __restrict__ res)
{
    int cls = blockIdx.y;
    int pd = (cls >> 2) & 1, ph = (cls >> 1) & 1, pw = cls & 1;
    int nh = 2 - ph, nw = 2 - pw, nhw = nh * nw;
    int ntap = (2 - pd) * nhw;
    int tid = threadIdx.x;
    int wv = tid >> 6, lane = tid & 63;
    int m = lane & 15, kq = lane >> 4;

    int n = cnt8[cls]; if (n > CAP) n = CAP;
    int ntiles = (n + 15) >> 4;

    float bv[7];
#pragma unroll
    for (int ct = 0; ct < 7; ct++) {
        int co = ct * 16 + m;
        bv[ct] = (co < 100) ? binv[co] : 0.f;
    }

    for (int t = blockIdx.x * 4 + wv; t < ntiles; t += 64 * 4) {
        int idx = t * 16 + m; if (idx >= n) idx = n - 1;
        unsigned int pv = (unsigned int)vox[cls * CAP + idx];
        int xx = pv & 127, yy = (pv >> 7) & 127, zz = (pv >> 14) & 127, bb = (pv >> 21) & 1;
        const unsigned short* abase = h2b +
            (size_t)(((((bb * DP + (zz >> 1) + pd) * DP + (yy >> 1) + ph) * DP
                       + (xx >> 1) + pw)) * C2 + kq * 8);

        floatx4 acc[7];
#pragma unroll
        for (int ct = 0; ct < 7; ct++) acc[ct] = (floatx4){0.f, 0.f, 0.f, 0.f};

        for (int tl = 0; tl < ntap; tl++) {
            int td = tl / nhw, rr = tl % nhw, th = rr / nw, tw = rr % nw;
            int tap = (pd + 2 * td) * 9 + (ph + 2 * th) * 3 + (pw + 2 * tw);
            short8 a = *(const short8*)(abase + ((td * DP + th) * DP + tw) * C2);
#pragma unroll
            for (int ct = 0; ct < 7; ct++) {
                short8 w = *(const short8*)(wb3 + ((tap * 7 + ct) * 64 + lane) * 8);
                acc[ct] = __builtin_amdgcn_mfma_f32_16x16x32_bf16(a, w, acc[ct], 0, 0, 0);
            }
        }
#pragma unroll
        for (int ct = 0; ct < 7; ct++) {
            int co = ct * 16 + m;
#pragma unroll
            for (int i = 0; i < 4; i++) {
                int ridx = t * 16 + kq * 4 + i;
                if (ridx < n)
                    res[(size_t)(cls * CAP + ridx) * 112 + co] = acc[ct][i] + bv[ct];
            }
        }
    }
}

// ---------------- k3write v6: LDS-tiled transpose writer, conflict-free (stride 113) ----------------
// grid (4292, 2): block = 64 consecutive flat positions x all 100 co.
// Gather: 4 threads/voxel read the full 448B res row (global float4, line-aligned, once),
//         commit as 28 scalar LDS writes (2-way banks = free).
// Store:  wave = 25 co-planes, lane = position; tile[lane*113+co] -> banks (17*lane+co)%32,
//         exactly 2 lanes/bank = conflict-free; 256B coalesced dword global stores.
__global__ __launch_bounds__(256) void k3write(
    const float* __restrict__ res, const int* __restrict__ sidxp,
    float* __restrict__ out)
{
    __shared__ float tile[64 * TW];   // 28.9 KB
    int blk = blockIdx.x;              // 0..4291
    int b = blockIdx.y;
    int r0 = blk * 64;
    int nv = D3IN - r0; if (nv > 64) nv = 64;
    int tid = threadIdx.x;

    int v = tid >> 2, q = tid & 3;
    if (v < nv) {
        int s = sidxp[b * D3P + r0 + v];
        float* dst = &tile[v * TW + q * 28];
        if (s >= 0) {
            union { float4 q4[7]; float f[28]; } u;
            const float4* src = (const float4*)(res + (size_t)s * 112 + q * 28);
#pragma unroll
            for (int j = 0; j < 7; j++) u.q4[j] = src[j];
#pragma unroll
            for (int k = 0; k < 28; k++) dst[k] = u.f[k];
        } else {
#pragma unroll
            for (int k = 0; k < 28; k++) dst[k] = 0.f;
        }
    }
    __syncthreads();

    int wv = tid >> 6, lane = tid & 63;
    if (lane < nv) {
        float* obase = out + (size_t)b * 100 * D3IN + r0 + lane;
#pragma unroll
        for (int j = 0; j < 25; j++) {
            int co = wv * 25 + j;
            obase[(size_t)co * D3IN] = tile[lane * TW + co];
        }
    }
}

extern "C" void kernel_launch(void* const* d_in, const int* in_sizes, int n_in,
                              void* d_out, int out_size, void* d_ws, size_t ws_size,
                              hipStream_t stream) {
    const float* x    = (const float*)d_in[0];
    const int*  mask0 = (const int*)  d_in[1];
    const float* W1   = (const float*)d_in[2];
    const float* b1   = (const float*)d_in[3];
    const float* g1   = (const float*)d_in[4];
    const float* bt1  = (const float*)d_in[5];
    const float* rm1  = (const float*)d_in[6];
    const float* rv1  = (const float*)d_in[7];
    const float* W2   = (const float*)d_in[8];
    const float* b2   = (const float*)d_in[9];
    const float* g2   = (const float*)d_in[10];
    const float* bt2  = (const float*)d_in[11];
    const float* rm2  = (const float*)d_in[12];
    const float* rv2  = (const float*)d_in[13];
    const float* Winv = (const float*)d_in[14];
    const float* binv = (const float*)d_in[15];

    float* ws = (float*)d_ws;
    unsigned short* h1b = (unsigned short*)(ws + H1B_OFF);
    unsigned short* h2b = (unsigned short*)(ws + H2B_OFF);
    float* m1   = ws + M1_OFF;
    unsigned short* wb2 = (unsigned short*)(ws + WB2_OFF);
    unsigned short* wb3 = (unsigned short*)(ws + WB3_OFF);
    int*   cnt8 = (int*)(ws + CNT8_OFF);
    int*   vox  = (int*)(ws + VOX_OFF);
    int*   sidxp= (int*)(ws + SIDX_OFF);
    float* res  = ws + RES_OFF;

    hipMemsetAsync(cnt8, 0, 8 * sizeof(int), stream);

    f1<<<1137, 256, 0, stream>>>(x, mask0, W1, b1, g1, bt1, rm1, rv1, W2, Winv,
                                 h1b, h2b, m1, wb2, wb3, sidxp, vox, cnt8);

    k2<<<1024, 256, 0, stream>>>(h1b, wb2, b2, g2, bt2, rm2, rv2, m1, h2b);

    k3compute<<<dim3(64, 8), 256, 0, stream>>>(h2b, wb3, binv, vox, cnt8, res);

    k3write<<<dim3(4292, 2), 256, 0, stream>>>(res, sidxp, (float*)d_out);
}

// Round 10
// 348.405 us; speedup vs baseline: 1.2538x; 1.0025x over previous
//
#include <hip/hip_runtime.h>

// ---- problem constants ----
#define BATCH 2
#define DIN 65
#define D2IN (65*65)
#define D3IN (65*65*65)
#define D3P 274628      // padded per-batch sidx stride (16B-aligned)
#define NTOT (2*D3IN)   // 549250
#define DO 32
#define DP 34           // padded 32 + 2 halo
#define C2 32
#define CO 100
#define CAP 8192        // per parity-class capacity
#define EPS 1e-5f
#define TS 68           // k3write tile stride over pos (16B-aligned rows, banks spread)

typedef __attribute__((ext_vector_type(8))) short short8;
typedef __attribute__((ext_vector_type(4))) float floatx4;
typedef __attribute__((ext_vector_type(4), aligned(4))) float f4u;  // 4B-aligned float4 store

// workspace layout (float offsets)
#define H1B_OFF 0                       // bf16 [2][34][34][34][32] -> 1257728 f
#define H2B_OFF 1257728
#define M1_OFF  2515456                 // 65536 f
#define WB2_OFF 2580992                 // 27*2*64*8 bf16 = 13824 f
#define WB3_OFF 2594816                 // 27*7*64*8 bf16 = 48384 f
#define CNT8_OFF (2643200)              // 8 ints (16B-aligned)
#define VOX_OFF 2643208                 // 65536 ints
#define SIDX_OFF 2708744                // 2*274628 = 549256 ints
#define RES_OFF 3258000                 // 16B-aligned; 65536*112 f
// total 10598032 floats ~= 42.4 MB

__device__ __forceinline__ unsigned short f2bf(float f) {
    unsigned int u = __float_as_uint(f);
    return (unsigned short)((u + 0x7fffu + ((u >> 16) & 1u)) >> 16);
}

// ================= F1: fused compact | k1 | shell-zero | weight-pack =================
// blocks [0,512): parity compact; [512,768): conv1; [768,1076): halo shell zero;
// [1076,1137): W2/Winv B-fragment packing. All parts write-disjoint.
__global__ __launch_bounds__(256) void f1(
    const float* __restrict__ x, const int* __restrict__ mask0,
    const float* __restrict__ W1, const float* __restrict__ b1,
    const float* __restrict__ g1, const float* __restrict__ bt1,
    const float* __restrict__ rm1, const float* __restrict__ rv1,
    const float* __restrict__ W2, const float* __restrict__ Winv,
    unsigned short* __restrict__ h1b, unsigned short* __restrict__ h2b,
    float* __restrict__ m1,
    unsigned short* __restrict__ wb2, unsigned short* __restrict__ wb3,
    int* __restrict__ sidxp, int* __restrict__ vox, int* __restrict__ cnt8)
{
    __shared__ int lcnt[8], lbase[8];
    int bid = blockIdx.x, tid = threadIdx.x;

    if (bid < 512) {
        // ---- parity-class compaction (cnt8 pre-zeroed by hipMemsetAsync) ----
        const int chunk = 1073;                 // 512*1073 >= NTOT
        int start = bid * chunk;
        int end = start + chunk; if (end > NTOT) end = NTOT;
        if (tid < 8) lcnt[tid] = 0;
        __syncthreads();
        for (int t = start + tid; t < end; t += 256) {
            if (mask0[t]) {
                int bb = (t >= D3IN) ? 1 : 0;
                int r = t - bb * D3IN;
                int z = r / D2IN; int rem = r % D2IN;
                int y = rem / DIN; int xx = rem % DIN;
                atomicAdd(&lcnt[((z & 1) << 2) | ((y & 1) << 1) | (xx & 1)], 1);
            }
        }
        __syncthreads();
        if (tid < 8) {
            lbase[tid] = lcnt[tid] ? atomicAdd(&cnt8[tid], lcnt[tid]) : 0;
            lcnt[tid] = 0;
        }
        __syncthreads();
        for (int t = start + tid; t < end; t += 256) {
            int bb = (t >= D3IN) ? 1 : 0;
            int r = t - bb * D3IN;
            int s = -1;
            if (mask0[t]) {
                int z = r / D2IN; int rem = r % D2IN;
                int y = rem / DIN; int xx = rem % DIN;
                int cls = ((z & 1) << 2) | ((y & 1) << 1) | (xx & 1);
                int loff = atomicAdd(&lcnt[cls], 1);
                int slot = lbase[cls] + loff;
                if (slot < CAP) {
                    s = cls * CAP + slot;
                    vox[s] = (bb << 21) | (z << 14) | (y << 7) | xx;
                }
            }
            sidxp[bb * D3P + r] = s;
        }
    } else if (bid < 768) {
        // ---- conv1(1->32,s2) + BN + ReLU + mask -> h1 bf16 (interior) ----
        int t = (bid - 512) * 256 + tid;   // 65536 voxels exactly
        int b = t >> 15, r = t & 32767;
        int z = r >> 10, y = (r >> 5) & 31, xo = r & 31;

        const float* xb = x + b * D3IN;
        const int*   mb = mask0 + b * D3IN;

        float xv[27];
        int any = 0;
#pragma unroll
        for (int kd = 0; kd < 3; kd++)
#pragma unroll
            for (int kh = 0; kh < 3; kh++) {
                int idx = (2 * z + kd) * D2IN + (2 * y + kh) * DIN + 2 * xo;
                float2 xa = *(const float2*)(xb + idx);
                float  xc = xb[idx + 2];
                int2   ma = *(const int2*)(mb + idx);
                int    mc = mb[idx + 2];
                int kb = kd * 9 + kh * 3;
                xv[kb] = xa.x; xv[kb + 1] = xa.y; xv[kb + 2] = xc;
                any |= ma.x | ma.y | mc;
            }
        float m1f = any ? 1.0f : 0.0f;
        m1[t] = m1f;

        union { unsigned short h[32]; uint4 v[4]; } u;
#pragma unroll 4
        for (int co = 0; co < 32; co++) {
            float a = 0.f;
#pragma unroll
            for (int k = 0; k < 27; k++) a += xv[k] * W1[co * 27 + k];
            float s = g1[co] * rsqrtf(rv1[co] + EPS);
            float v = (a + b1[co] - rm1[co]) * s + bt1[co];
            u.h[co] = f2bf(fmaxf(v, 0.f) * m1f);
        }
        uint4* out4 = (uint4*)(h1b + (size_t)((((b * DP + z + 1) * DP + (y + 1)) * DP + (xo + 1)) * C2));
#pragma unroll
        for (int q = 0; q < 4; q++) out4[q] = u.v[q];
    } else if (bid < 1076) {
        // ---- halo shell zero for h1b and h2b ----
        int gid = (bid - 768) * 256 + tid;
        if (gid < 2 * 39304) {
            int b = gid / 39304; int r = gid % 39304;
            int z = r / 1156; int rem = r % 1156;
            int y = rem / 34; int xx = rem % 34;
            if (z == 0 || z == 33 || y == 0 || y == 33 || xx == 0 || xx == 33) {
                size_t off = (size_t)((((b * DP + z) * DP + y) * DP + xx) * C2);
                uint4 zv; zv.x = 0; zv.y = 0; zv.z = 0; zv.w = 0;
                uint4* p1 = (uint4*)(h1b + off);
                uint4* p2 = (uint4*)(h2b + off);
#pragma unroll
                for (int q = 0; q < 4; q++) { p1[q] = zv; p2[q] = zv; }
            }
        }
    } else {
        // ---- pack W2 / Winv into MFMA B-fragment layout ----
        int gid = (bid - 1076) * 256 + tid;
        if (gid < 27 * 2 * 64) {
            int q = gid;
            int tap = q >> 7, r = q & 127, ct = r >> 6, lane = r & 63;
            int n = ct * 16 + (lane & 15), kq = lane >> 4;
            union { unsigned short h[8]; uint4 v; } u;
#pragma unroll
            for (int j = 0; j < 8; j++) {
                int k = kq * 8 + j;
                u.h[j] = f2bf(W2[n * 864 + k * 27 + tap]);
            }
            *(uint4*)(wb2 + q * 8) = u.v;
        } else if (gid < 27 * 2 * 64 + 27 * 7 * 64) {
            int q = gid - 27 * 2 * 64;
            int tap = q / 448, r = q % 448, ct = r >> 6, lane = r & 63;
            int co = ct * 16 + (lane & 15), kq = lane >> 4;
            union { unsigned short h[8]; uint4 v; } u;
#pragma unroll
            for (int j = 0; j < 8; j++) {
                int k = kq * 8 + j;
                u.h[j] = (co < 100) ? f2bf(Winv[(co * 32 + k) * 27 + tap]) : (unsigned short)0;
            }
            *(uint4*)(wb3 + q * 8) = u.v;
        }
    }
}

// ---------------- k2: conv2 as MFMA gather-GEMM; h2 bf16 out ----------------
__global__ __launch_bounds__(256) void k2(
    const unsigned short* __restrict__ h1b, const unsigned short* __restrict__ wb2,
    const float* __restrict__ b2, const float* __restrict__ g2,
    const float* __restrict__ bt2, const float* __restrict__ rm2,
    const float* __restrict__ rv2, const float* __restrict__ m1,
    unsigned short* __restrict__ h2b)
{
    int tid = threadIdx.x;
    int wv = tid >> 6, lane = tid & 63;
    int mtile = blockIdx.x * 4 + wv;      // [0,4096)
    int v0 = mtile * 16;
    int b = v0 >> 15, r = v0 & 32767;
    int z = r >> 10, y = (r >> 5) & 31, x0 = r & 31;

    int m = lane & 15, kq = lane >> 4;
    const unsigned short* abase = h1b +
        (size_t)((((b * DP + z) * DP + y) * DP + x0 + m) * C2 + kq * 8);

    floatx4 acc[2];
    acc[0] = (floatx4){0.f, 0.f, 0.f, 0.f};
    acc[1] = (floatx4){0.f, 0.f, 0.f, 0.f};

    for (int kd = 0; kd < 3; kd++)
#pragma unroll
        for (int kh = 0; kh < 3; kh++)
#pragma unroll
            for (int kw = 0; kw < 3; kw++) {
                int tap = (kd * 3 + kh) * 3 + kw;
                short8 a = *(const short8*)(abase + ((kd * DP + kh) * DP + kw) * C2);
                short8 w0 = *(const short8*)(wb2 + ((tap * 2 + 0) * 64 + lane) * 8);
                short8 w1 = *(const short8*)(wb2 + ((tap * 2 + 1) * 64 + lane) * 8);
                acc[0] = __builtin_amdgcn_mfma_f32_16x16x32_bf16(a, w0, acc[0], 0, 0, 0);
                acc[1] = __builtin_amdgcn_mfma_f32_16x16x32_bf16(a, w1, acc[1], 0, 0, 0);
            }

    float mf[4];
#pragma unroll
    for (int i = 0; i < 4; i++) mf[i] = m1[v0 + kq * 4 + i];
#pragma unroll
    for (int ct = 0; ct < 2; ct++) {
        int co = ct * 16 + m;
        float s = g2[co] * rsqrtf(rv2[co] + EPS);
        float sh = (b2[co] - rm2[co]) * s + bt2[co];
#pragma unroll
        for (int i = 0; i < 4; i++) {
            int row = kq * 4 + i;
            float val = fmaxf(acc[ct][i] * s + sh, 0.f) * mf[i];
            h2b[(size_t)((((b * DP + z + 1) * DP + (y + 1)) * DP + (x0 + row + 1)) * C2 + co)]
                = f2bf(val);
        }
    }
}

// ---------------- k3compute: inverse conv as MFMA gather-GEMM; res stride 112 ----------------
__global__ __launch_bounds__(256) void k3compute(
    const unsigned short* __restrict__ h2b, const unsigned short* __restrict__ wb3,
    const float* __restrict__ binv, const int* __restrict__ vox,
    const int* __restrict__ cnt8, float* __restrict__ res)
{
    int cls = blockIdx.y;
    int pd = (cls >> 2) & 1, ph = (cls >> 1) & 1, pw = cls & 1;
    int nh = 2 - ph, nw = 2 - pw, nhw = nh * nw;
    int ntap = (2 - pd) * nhw;
    int tid = threadIdx.x;
    int wv = tid >> 6, lane = tid & 63;
    int m = lane & 15, kq = lane >> 4;

    int n = cnt8[cls]; if (n > CAP) n = CAP;
    int ntiles = (n + 15) >> 4;

    float bv[7];
#pragma unroll
    for (int ct = 0; ct < 7; ct++) {
        int co = ct * 16 + m;
        bv[ct] = (co < 100) ? binv[co] : 0.f;
    }

    for (int t = blockIdx.x * 4 + wv; t < ntiles; t += 64 * 4) {
        int idx = t * 16 + m; if (idx >= n) idx = n - 1;
        unsigned int pv = (unsigned int)vox[cls * CAP + idx];
        int xx = pv & 127, yy = (pv >> 7) & 127, zz = (pv >> 14) & 127, bb = (pv >> 21) & 1;
        const unsigned short* abase = h2b +
            (size_t)(((((bb * DP + (zz >> 1) + pd) * DP + (yy >> 1) + ph) * DP
                       + (xx >> 1) + pw)) * C2 + kq * 8);

        floatx4 acc[7];
#pragma unroll
        for (int ct = 0; ct < 7; ct++) acc[ct] = (floatx4){0.f, 0.f, 0.f, 0.f};

        for (int tl = 0; tl < ntap; tl++) {
            int td = tl / nhw, rr = tl % nhw, th = rr / nw, tw = rr % nw;
            int tap = (pd + 2 * td) * 9 + (ph + 2 * th) * 3 + (pw + 2 * tw);
            short8 a = *(const short8*)(abase + ((td * DP + th) * DP + tw) * C2);
#pragma unroll
            for (int ct = 0; ct < 7; ct++) {
                short8 w = *(const short8*)(wb3 + ((tap * 7 + ct) * 64 + lane) * 8);
                acc[ct] = __builtin_amdgcn_mfma_f32_16x16x32_bf16(a, w, acc[ct], 0, 0, 0);
            }
        }
#pragma unroll
        for (int ct = 0; ct < 7; ct++) {
            int co = ct * 16 + m;
#pragma unroll
            for (int i = 0; i < 4; i++) {
                int ridx = t * 16 + kq * 4 + i;
                if (ridx < n)
                    res[(size_t)(cls * CAP + ridx) * 112 + co] = acc[ct][i] + bv[ct];
            }
        }
    }
}

// ---------------- k3write v8: transposed [co][pos] tile, b128 LDS reads, x4 stores ----------------
// grid (4292, 2): block = 64 consecutive flat positions x all 100 co.
// Gather: 4 threads/voxel read the full 448B res row once, scatter into tile[co*TS+pos]
//         (banks (4co+v)%32, ~2-way = free).
// Store:  lane = (c4, xq): co = p*16+wv*4+c4, pos = 4*xq; ds_read_b128 (16B-aligned,
//         bank-balanced) + 4B-aligned dwordx4 global store (D3IN odd -> planes only 4B-aligned).
__global__ __launch_bounds__(256) void k3write(
    const float* __restrict__ res, const int* __restrict__ sidxp,
    float* __restrict__ out)
{
    __shared__ float tile[100 * TS];   // 27.2 KB
    int blk = blockIdx.x;              // 0..4291
    int b = blockIdx.y;
    int r0 = blk * 64;
    int nv = D3IN - r0; if (nv > 64) nv = 64;
    int tid = threadIdx.x;

    int v = tid >> 2, q = tid & 3;
    if (v < nv) {
        int s = sidxp[b * D3P + r0 + v];
        if (s >= 0) {
            union { float4 q4[7]; float f[28]; } u;
            const float4* src = (const float4*)(res + (size_t)s * 112 + q * 28);
#pragma unroll
            for (int j = 0; j < 7; j++) u.q4[j] = src[j];
#pragma unroll
            for (int k = 0; k < 28; k++) {
                int co = q * 28 + k;
                if (co < 100) tile[co * TS + v] = u.f[k];
            }
        } else {
#pragma unroll
            for (int k = 0; k < 28; k++) {
                int co = q * 28 + k;
                if (co < 100) tile[co * TS + v] = 0.f;
            }
        }
    }
    __syncthreads();

    int wv = tid >> 6, lane = tid & 63;
    int c4 = lane >> 4, xq = lane & 15;
    int pos = 4 * xq;
#pragma unroll
    for (int p = 0; p < 7; p++) {
        int co = p * 16 + wv * 4 + c4;
        if (co < 100) {
            floatx4 vv = *(const floatx4*)&tile[co * TS + pos];
            size_t ob = ((size_t)b * 100 + co) * D3IN + r0 + pos;
            if (pos + 3 < nv) {
                *(f4u*)(out + ob) = vv;           // 4B-aligned dwordx4
            } else if (pos < nv) {
                int nrem = nv - pos;
                for (int k = 0; k < nrem; k++) out[ob + k] = vv[k];
            }
        }
    }
}

extern "C" void kernel_launch(void* const* d_in, const int* in_sizes, int n_in,
                              void* d_out, int out_size, void* d_ws, size_t ws_size,
                              hipStream_t stream) {
    const float* x    = (const float*)d_in[0];
    const int*  mask0 = (const int*)  d_in[1];
    const float* W1   = (const float*)d_in[2];
    const float* b1   = (const float*)d_in[3];
    const float* g1   = (const float*)d_in[4];
    const float* bt1  = (const float*)d_in[5];
    const float* rm1  = (const float*)d_in[6];
    const float* rv1  = (const float*)d_in[7];
    const float* W2   = (const float*)d_in[8];
    const float* b2   = (const float*)d_in[9];
    const float* g2   = (const float*)d_in[10];
    const float* bt2  = (const float*)d_in[11];
    const float* rm2  = (const float*)d_in[12];
    const float* rv2  = (const float*)d_in[13];
    const float* Winv = (const float*)d_in[14];
    const float* binv = (const float*)d_in[15];

    float* ws = (float*)d_ws;
    unsigned short* h1b = (unsigned short*)(ws + H1B_OFF);
    unsigned short* h2b = (unsigned short*)(ws + H2B_OFF);
    float* m1   = ws + M1_OFF;
    unsigned short* wb2 = (unsigned short*)(ws + WB2_OFF);
    unsigned short* wb3 = (unsigned short*)(ws + WB3_OFF);
    int*   cnt8 = (int*)(ws + CNT8_OFF);
    int*   vox  = (int*)(ws + VOX_OFF);
    int*   sidxp= (int*)(ws + SIDX_OFF);
    float* res  = ws + RES_OFF;

    hipMemsetAsync(cnt8, 0, 8 * sizeof(int), stream);

    f1<<<1137, 256, 0, stream>>>(x, mask0, W1, b1, g1, bt1, rm1, rv1, W2, Winv,
                                 h1b, h2b, m1, wb2, wb3, sidxp, vox, cnt8);

    k2<<<1024, 256, 0, stream>>>(h1b, wb2, b2, g2, bt2, rm2, rv2, m1, h2b);

    k3compute<<<dim3(64, 8), 256, 0, stream>>>(h2b, wb3, binv, vox, cnt8, res);

    k3write<<<dim3(4292, 2), 256, 0, stream>>>(res, sidxp, (float*)d_out);
}

// Round 11
// 340.720 us; speedup vs baseline: 1.2821x; 1.0226x over previous
//
#include <hip/hip_runtime.h>

// ---- problem constants ----
#define BATCH 2
#define DIN 65
#define D2IN (65*65)
#define D3IN (65*65*65)
#define D3P 274628      // padded per-batch sidx stride (16B-aligned)
#define NTOT (2*D3IN)   // 549250
#define DO 32
#define DP 34           // padded 32 + 2 halo
#define C2 32
#define CO 100
#define CAP 8192        // per parity-class capacity
#define EPS 1e-5f
#define TS 68           // k3write tile stride over pos (16B-aligned rows, banks spread)
#define NB3 256         // k3compute grid.x (2048 blocks total = 8/CU)

typedef __attribute__((ext_vector_type(8))) short short8;
typedef __attribute__((ext_vector_type(4))) float floatx4;
typedef __attribute__((ext_vector_type(4), aligned(4))) float f4u;  // 4B-aligned float4 store

// workspace layout (float offsets)
#define H1B_OFF 0                       // bf16 [2][34][34][34][32] -> 1257728 f
#define H2B_OFF 1257728
#define M1_OFF  2515456                 // 65536 f
#define WB2_OFF 2580992                 // 27*2*64*8 bf16 = 13824 f
#define WB3_OFF 2594816                 // 27*7*64*8 bf16 = 48384 f
#define CNT8_OFF (2643200)              // 8 ints (16B-aligned)
#define VOX_OFF 2643208                 // 65536 ints
#define SIDX_OFF 2708744                // 2*274628 = 549256 ints
#define RES_OFF 3258000                 // 16B-aligned; 65536*112 f
// total 10598032 floats ~= 42.4 MB

__device__ __forceinline__ unsigned short f2bf(float f) {
    unsigned int u = __float_as_uint(f);
    return (unsigned short)((u + 0x7fffu + ((u >> 16) & 1u)) >> 16);
}

// ================= F1: fused compact | k1 | shell-zero | weight-pack =================
// blocks [0,512): parity compact; [512,768): conv1; [768,1076): halo shell zero;
// [1076,1137): W2/Winv B-fragment packing. All parts write-disjoint.
__global__ __launch_bounds__(256) void f1(
    const float* __restrict__ x, const int* __restrict__ mask0,
    const float* __restrict__ W1, const float* __restrict__ b1,
    const float* __restrict__ g1, const float* __restrict__ bt1,
    const float* __restrict__ rm1, const float* __restrict__ rv1,
    const float* __restrict__ W2, const float* __restrict__ Winv,
    unsigned short* __restrict__ h1b, unsigned short* __restrict__ h2b,
    float* __restrict__ m1,
    unsigned short* __restrict__ wb2, unsigned short* __restrict__ wb3,
    int* __restrict__ sidxp, int* __restrict__ vox, int* __restrict__ cnt8)
{
    __shared__ int lcnt[8], lbase[8];
    int bid = blockIdx.x, tid = threadIdx.x;

    if (bid < 512) {
        // ---- parity-class compaction (cnt8 pre-zeroed by hipMemsetAsync) ----
        const int chunk = 1073;                 // 512*1073 >= NTOT
        int start = bid * chunk;
        int end = start + chunk; if (end > NTOT) end = NTOT;
        if (tid < 8) lcnt[tid] = 0;
        __syncthreads();
        for (int t = start + tid; t < end; t += 256) {
            if (mask0[t]) {
                int bb = (t >= D3IN) ? 1 : 0;
                int r = t - bb * D3IN;
                int z = r / D2IN; int rem = r % D2IN;
                int y = rem / DIN; int xx = rem % DIN;
                atomicAdd(&lcnt[((z & 1) << 2) | ((y & 1) << 1) | (xx & 1)], 1);
            }
        }
        __syncthreads();
        if (tid < 8) {
            lbase[tid] = lcnt[tid] ? atomicAdd(&cnt8[tid], lcnt[tid]) : 0;
            lcnt[tid] = 0;
        }
        __syncthreads();
        for (int t = start + tid; t < end; t += 256) {
            int bb = (t >= D3IN) ? 1 : 0;
            int r = t - bb * D3IN;
            int s = -1;
            if (mask0[t]) {
                int z = r / D2IN; int rem = r % D2IN;
                int y = rem / DIN; int xx = rem % DIN;
                int cls = ((z & 1) << 2) | ((y & 1) << 1) | (xx & 1);
                int loff = atomicAdd(&lcnt[cls], 1);
                int slot = lbase[cls] + loff;
                if (slot < CAP) {
                    s = cls * CAP + slot;
                    vox[s] = (bb << 21) | (z << 14) | (y << 7) | xx;
                }
            }
            sidxp[bb * D3P + r] = s;
        }
    } else if (bid < 768) {
        // ---- conv1(1->32,s2) + BN + ReLU + mask -> h1 bf16 (interior) ----
        int t = (bid - 512) * 256 + tid;   // 65536 voxels exactly
        int b = t >> 15, r = t & 32767;
        int z = r >> 10, y = (r >> 5) & 31, xo = r & 31;

        const float* xb = x + b * D3IN;
        const int*   mb = mask0 + b * D3IN;

        float xv[27];
        int any = 0;
#pragma unroll
        for (int kd = 0; kd < 3; kd++)
#pragma unroll
            for (int kh = 0; kh < 3; kh++) {
                int idx = (2 * z + kd) * D2IN + (2 * y + kh) * DIN + 2 * xo;
                float2 xa = *(const float2*)(xb + idx);
                float  xc = xb[idx + 2];
                int2   ma = *(const int2*)(mb + idx);
                int    mc = mb[idx + 2];
                int kb = kd * 9 + kh * 3;
                xv[kb] = xa.x; xv[kb + 1] = xa.y; xv[kb + 2] = xc;
                any |= ma.x | ma.y | mc;
            }
        float m1f = any ? 1.0f : 0.0f;
        m1[t] = m1f;

        union { unsigned short h[32]; uint4 v[4]; } u;
#pragma unroll 4
        for (int co = 0; co < 32; co++) {
            float a = 0.f;
#pragma unroll
            for (int k = 0; k < 27; k++) a += xv[k] * W1[co * 27 + k];
            float s = g1[co] * rsqrtf(rv1[co] + EPS);
            float v = (a + b1[co] - rm1[co]) * s + bt1[co];
            u.h[co] = f2bf(fmaxf(v, 0.f) * m1f);
        }
        uint4* out4 = (uint4*)(h1b + (size_t)((((b * DP + z + 1) * DP + (y + 1)) * DP + (xo + 1)) * C2));
#pragma unroll
        for (int q = 0; q < 4; q++) out4[q] = u.v[q];
    } else if (bid < 1076) {
        // ---- halo shell zero for h1b and h2b ----
        int gid = (bid - 768) * 256 + tid;
        if (gid < 2 * 39304) {
            int b = gid / 39304; int r = gid % 39304;
            int z = r / 1156; int rem = r % 1156;
            int y = rem / 34; int xx = rem % 34;
            if (z == 0 || z == 33 || y == 0 || y == 33 || xx == 0 || xx == 33) {
                size_t off = (size_t)((((b * DP + z) * DP + y) * DP + xx) * C2);
                uint4 zv; zv.x = 0; zv.y = 0; zv.z = 0; zv.w = 0;
                uint4* p1 = (uint4*)(h1b + off);
                uint4* p2 = (uint4*)(h2b + off);
#pragma unroll
                for (int q = 0; q < 4; q++) { p1[q] = zv; p2[q] = zv; }
            }
        }
    } else {
        // ---- pack W2 / Winv into MFMA B-fragment layout ----
        int gid = (bid - 1076) * 256 + tid;
        if (gid < 27 * 2 * 64) {
            int q = gid;
            int tap = q >> 7, r = q & 127, ct = r >> 6, lane = r & 63;
            int n = ct * 16 + (lane & 15), kq = lane >> 4;
            union { unsigned short h[8]; uint4 v; } u;
#pragma unroll
            for (int j = 0; j < 8; j++) {
                int k = kq * 8 + j;
                u.h[j] = f2bf(W2[n * 864 + k * 27 + tap]);
            }
            *(uint4*)(wb2 + q * 8) = u.v;
        } else if (gid < 27 * 2 * 64 + 27 * 7 * 64) {
            int q = gid - 27 * 2 * 64;
            int tap = q / 448, r = q % 448, ct = r >> 6, lane = r & 63;
            int co = ct * 16 + (lane & 15), kq = lane >> 4;
            union { unsigned short h[8]; uint4 v; } u;
#pragma unroll
            for (int j = 0; j < 8; j++) {
                int k = kq * 8 + j;
                u.h[j] = (co < 100) ? f2bf(Winv[(co * 32 + k) * 27 + tap]) : (unsigned short)0;
            }
            *(uint4*)(wb3 + q * 8) = u.v;
        }
    }
}

// ---------------- k2: conv2 as MFMA gather-GEMM; h2 bf16 out ----------------
__global__ __launch_bounds__(256) void k2(
    const unsigned short* __restrict__ h1b, const unsigned short* __restrict__ wb2,
    const float* __restrict__ b2, const float* __restrict__ g2,
    const float* __restrict__ bt2, const float* __restrict__ rm2,
    const float* __restrict__ rv2, const float* __restrict__ m1,
    unsigned short* __restrict__ h2b)
{
    int tid = threadIdx.x;
    int wv = tid >> 6, lane = tid & 63;
    int mtile = blockIdx.x * 4 + wv;      // [0,4096)
    int v0 = mtile * 16;
    int b = v0 >> 15, r = v0 & 32767;
    int z = r >> 10, y = (r >> 5) & 31, x0 = r & 31;

    int m = lane & 15, kq = lane >> 4;
    const unsigned short* abase = h1b +
        (size_t)((((b * DP + z) * DP + y) * DP + x0 + m) * C2 + kq * 8);

    floatx4 acc[2];
    acc[0] = (floatx4){0.f, 0.f, 0.f, 0.f};
    acc[1] = (floatx4){0.f, 0.f, 0.f, 0.f};

    for (int kd = 0; kd < 3; kd++)
#pragma unroll
        for (int kh = 0; kh < 3; kh++)
#pragma unroll
            for (int kw = 0; kw < 3; kw++) {
                int tap = (kd * 3 + kh) * 3 + kw;
                short8 a = *(const short8*)(abase + ((kd * DP + kh) * DP + kw) * C2);
                short8 w0 = *(const short8*)(wb2 + ((tap * 2 + 0) * 64 + lane) * 8);
                short8 w1 = *(const short8*)(wb2 + ((tap * 2 + 1) * 64 + lane) * 8);
                acc[0] = __builtin_amdgcn_mfma_f32_16x16x32_bf16(a, w0, acc[0], 0, 0, 0);
                acc[1] = __builtin_amdgcn_mfma_f32_16x16x32_bf16(a, w1, acc[1], 0, 0, 0);
            }

    float mf[4];
#pragma unroll
    for (int i = 0; i < 4; i++) mf[i] = m1[v0 + kq * 4 + i];
#pragma unroll
    for (int ct = 0; ct < 2; ct++) {
        int co = ct * 16 + m;
        float s = g2[co] * rsqrtf(rv2[co] + EPS);
        float sh = (b2[co] - rm2[co]) * s + bt2[co];
#pragma unroll
        for (int i = 0; i < 4; i++) {
            int row = kq * 4 + i;
            float val = fmaxf(acc[ct][i] * s + sh, 0.f) * mf[i];
            h2b[(size_t)((((b * DP + z + 1) * DP + (y + 1)) * DP + (x0 + row + 1)) * C2 + co)]
                = f2bf(val);
        }
    }
}

// ---------------- k3compute: inverse conv as MFMA gather-GEMM; res stride 112 ----------------
// grid (NB3=256, 8) = 2048 blocks = 8 blocks/CU = 32 waves/CU (was 2 blocks/CU —
// latency-bound: per-tile dependent chain vox->decode->global a-load->MFMA).
__global__ __launch_bounds__(256) void k3compute(
    const unsigned short* __restrict__ h2b, const unsigned short* __restrict__ wb3,
    const float* __restrict__ binv, const int* __restrict__ vox,
    const int* __restrict__ cnt8, float* __restrict__ res)
{
    int cls = blockIdx.y;
    int pd = (cls >> 2) & 1, ph = (cls >> 1) & 1, pw = cls & 1;
    int nh = 2 - ph, nw = 2 - pw, nhw = nh * nw;
    int ntap = (2 - pd) * nhw;
    int tid = threadIdx.x;
    int wv = tid >> 6, lane = tid & 63;
    int m = lane & 15, kq = lane >> 4;

    int n = cnt8[cls]; if (n > CAP) n = CAP;
    int ntiles = (n + 15) >> 4;

    float bv[7];
#pragma unroll
    for (int ct = 0; ct < 7; ct++) {
        int co = ct * 16 + m;
        bv[ct] = (co < 100) ? binv[co] : 0.f;
    }

    for (int t = blockIdx.x * 4 + wv; t < ntiles; t += NB3 * 4) {
        int idx = t * 16 + m; if (idx >= n) idx = n - 1;
        unsigned int pv = (unsigned int)vox[cls * CAP + idx];
        int xx = pv & 127, yy = (pv >> 7) & 127, zz = (pv >> 14) & 127, bb = (pv >> 21) & 1;
        const unsigned short* abase = h2b +
            (size_t)(((((bb * DP + (zz >> 1) + pd) * DP + (yy >> 1) + ph) * DP
                       + (xx >> 1) + pw)) * C2 + kq * 8);

        floatx4 acc[7];
#pragma unroll
        for (int ct = 0; ct < 7; ct++) acc[ct] = (floatx4){0.f, 0.f, 0.f, 0.f};

        for (int tl = 0; tl < ntap; tl++) {
            int td = tl / nhw, rr = tl % nhw, th = rr / nw, tw = rr % nw;
            int tap = (pd + 2 * td) * 9 + (ph + 2 * th) * 3 + (pw + 2 * tw);
            short8 a = *(const short8*)(abase + ((td * DP + th) * DP + tw) * C2);
#pragma unroll
            for (int ct = 0; ct < 7; ct++) {
                short8 w = *(const short8*)(wb3 + ((tap * 7 + ct) * 64 + lane) * 8);
                acc[ct] = __builtin_amdgcn_mfma_f32_16x16x32_bf16(a, w, acc[ct], 0, 0, 0);
            }
        }
#pragma unroll
        for (int ct = 0; ct < 7; ct++) {
            int co = ct * 16 + m;
#pragma unroll
            for (int i = 0; i < 4; i++) {
                int ridx = t * 16 + kq * 4 + i;
                if (ridx < n)
                    res[(size_t)(cls * CAP + ridx) * 112 + co] = acc[ct][i] + bv[ct];
            }
        }
    }
}

// ---------------- k3write v8: transposed [co][pos] tile, b128 LDS reads, x4 stores ----------------
// grid (4292, 2): block = 64 consecutive flat positions x all 100 co.
__global__ __launch_bounds__(256) void k3write(
    const float* __restrict__ res, const int* __restrict__ sidxp,
    float* __restrict__ out)
{
    __shared__ float tile[100 * TS];   // 27.2 KB
    int blk = blockIdx.x;              // 0..4291
    int b = blockIdx.y;
    int r0 = blk * 64;
    int nv = D3IN - r0; if (nv > 64) nv = 64;
    int tid = threadIdx.x;

    int v = tid >> 2, q = tid & 3;
    if (v < nv) {
        int s = sidxp[b * D3P + r0 + v];
        if (s >= 0) {
            union { float4 q4[7]; float f[28]; } u;
            const float4* src = (const float4*)(res + (size_t)s * 112 + q * 28);
#pragma unroll
            for (int j = 0; j < 7; j++) u.q4[j] = src[j];
#pragma unroll
            for (int k = 0; k < 28; k++) {
                int co = q * 28 + k;
                if (co < 100) tile[co * TS + v] = u.f[k];
            }
        } else {
#pragma unroll
            for (int k = 0; k < 28; k++) {
                int co = q * 28 + k;
                if (co < 100) tile[co * TS + v] = 0.f;
            }
        }
    }
    __syncthreads();

    int wv = tid >> 6, lane = tid & 63;
    int c4 = lane >> 4, xq = lane & 15;
    int pos = 4 * xq;
#pragma unroll
    for (int p = 0; p < 7; p++) {
        int co = p * 16 + wv * 4 + c4;
        if (co < 100) {
            floatx4 vv = *(const floatx4*)&tile[co * TS + pos];
            size_t ob = ((size_t)b * 100 + co) * D3IN + r0 + pos;
            if (pos + 3 < nv) {
                *(f4u*)(out + ob) = vv;           // 4B-aligned dwordx4
            } else if (pos < nv) {
                int nrem = nv - pos;
                for (int k = 0; k < nrem; k++) out[ob + k] = vv[k];
            }
        }
    }
}

extern "C" void kernel_launch(void* const* d_in, const int* in_sizes, int n_in,
                              void* d_out, int out_size, void* d_ws, size_t ws_size,
                              hipStream_t stream) {
    const float* x    = (const float*)d_in[0];
    const int*  mask0 = (const int*)  d_in[1];
    const float* W1   = (const float*)d_in[2];
    const float* b1   = (const float*)d_in[3];
    const float* g1   = (const float*)d_in[4];
    const float* bt1  = (const float*)d_in[5];
    const float* rm1  = (const float*)d_in[6];
    const float* rv1  = (const float*)d_in[7];
    const float* W2   = (const float*)d_in[8];
    const float* b2   = (const float*)d_in[9];
    const float* g2   = (const float*)d_in[10];
    const float* bt2  = (const float*)d_in[11];
    const float* rm2  = (const float*)d_in[12];
    const float* rv2  = (const float*)d_in[13];
    const float* Winv = (const float*)d_in[14];
    const float* binv = (const float*)d_in[15];

    float* ws = (float*)d_ws;
    unsigned short* h1b = (unsigned short*)(ws + H1B_OFF);
    unsigned short* h2b = (unsigned short*)(ws + H2B_OFF);
    float* m1   = ws + M1_OFF;
    unsigned short* wb2 = (unsigned short*)(ws + WB2_OFF);
    unsigned short* wb3 = (unsigned short*)(ws + WB3_OFF);
    int*   cnt8 = (int*)(ws + CNT8_OFF);
    int*   vox  = (int*)(ws + VOX_OFF);
    int*   sidxp= (int*)(ws + SIDX_OFF);
    float* res  = ws + RES_OFF;

    hipMemsetAsync(cnt8, 0, 8 * sizeof(int), stream);

    f1<<<1137, 256, 0, stream>>>(x, mask0, W1, b1, g1, bt1, rm1, rv1, W2, Winv,
                                 h1b, h2b, m1, wb2, wb3, sidxp, vox, cnt8);

    k2<<<1024, 256, 0, stream>>>(h1b, wb2, b2, g2, bt2, rm2, rv2, m1, h2b);

    k3compute<<<dim3(NB3, 8), 256, 0, stream>>>(h2b, wb3, binv, vox, cnt8, res);

    k3write<<<dim3(4292, 2), 256, 0, stream>>>(res, sidxp, (float*)d_out);
}